// Round 2
// baseline (431.847 us; speedup 1.0000x reference)
//
#include <hip/hip_runtime.h>

// LinearAttentionBlock: B=8 T=512 FIN=256 D=128
// out   [B,T,D]    @ d_out + 0
// S_out [B,T,D*D]  @ d_out + 524288      (256 MiB -> HBM-write bound floor ~43us)
// Z     [B,T,D]    @ d_out + 524288 + 67108864

constexpr int BB = 8, TT = 512, FIN_ = 256, DD = 128;
constexpr int NROW = BB * TT;       // 4096
constexpr int CLEN = 64, NCH = 8;   // chunk length, chunks per batch (T = CLEN*NCH)
constexpr float CLAMPV = 1e20f;

// ---------------- 1. LayerNorm (one block per row, 256 threads = FIN) ----------------
__global__ __launch_bounds__(256) void ln_kernel(
    const float* __restrict__ x, const float* __restrict__ gamma,
    const float* __restrict__ beta, float* __restrict__ xn)
{
  int row = blockIdx.x, tid = threadIdx.x;
  float v = x[row * FIN_ + tid];
  __shared__ float s1[256], s2[256];
  s1[tid] = v; s2[tid] = v * v;
  __syncthreads();
  for (int s = 128; s > 0; s >>= 1) {
    if (tid < s) { s1[tid] += s1[tid + s]; s2[tid] += s2[tid + s]; }
    __syncthreads();
  }
  float mu  = s1[0] * (1.0f / FIN_);
  float var = s2[0] * (1.0f / FIN_) - mu * mu;
  float rs  = rsqrtf(var + 1e-5f);
  xn[row * FIN_ + tid] = (v - mu) * rs * gamma[tid] + beta[tid];
}

// ---------------- 2. xn @ {Wk,Wq,Wv,Ws} fused GEMM, 64x64 tiles, 4x4 micro ----------------
// grid.x = 8 col-tiles (mat = ct>>1, 64-col half = ct&1), grid.y = 64 row-tiles
__global__ __launch_bounds__(256) void gemm_qkvs(
    const float* __restrict__ xn,
    const float* __restrict__ Wk, const float* __restrict__ Wq,
    const float* __restrict__ Wv, const float* __restrict__ Ws,
    const float* __restrict__ bs,
    float* __restrict__ Kb, float* __restrict__ Qb,
    float* __restrict__ Vb, float* __restrict__ Rb)
{
  int ct = blockIdx.x, rt = blockIdx.y;
  int mat = ct >> 1, cb = (ct & 1) * 64;
  const float* W = (mat == 0) ? Wk : (mat == 1) ? Wq : (mat == 2) ? Wv : Ws;
  float* Ob      = (mat == 0) ? Kb : (mat == 1) ? Qb : (mat == 2) ? Vb : Rb;
  __shared__ float As[16][64];   // [k][m]
  __shared__ float Bs[16][64];   // [k][n]
  int tid = threadIdx.x;
  int tn = tid & 15, tm = tid >> 4;
  int lm = tid >> 2, lq = tid & 3;          // A-load: row, k-quad
  int lk = tid >> 4, ln4 = (tid & 15) * 4;  // B-load: k, n-quad
  float acc[4][4] = {};
  for (int k0 = 0; k0 < FIN_; k0 += 16) {
    float4 av = *(const float4*)&xn[(rt * 64 + lm) * FIN_ + k0 + lq * 4];
    As[lq * 4 + 0][lm] = av.x;
    As[lq * 4 + 1][lm] = av.y;
    As[lq * 4 + 2][lm] = av.z;
    As[lq * 4 + 3][lm] = av.w;
    *(float4*)&Bs[lk][ln4] = *(const float4*)&W[(k0 + lk) * DD + cb + ln4];
    __syncthreads();
#pragma unroll
    for (int k = 0; k < 16; k++) {
      float4 a = *(const float4*)&As[k][tm * 4];
      float4 b = *(const float4*)&Bs[k][tn * 4];
      float ar[4] = {a.x, a.y, a.z, a.w};
      float br[4] = {b.x, b.y, b.z, b.w};
#pragma unroll
      for (int i = 0; i < 4; i++)
#pragma unroll
        for (int j = 0; j < 4; j++) acc[i][j] += ar[i] * br[j];
    }
    __syncthreads();
  }
#pragma unroll
  for (int i = 0; i < 4; i++) {
    int row = rt * 64 + tm * 4 + i;
    int col = cb + tn * 4;
    float vals[4];
#pragma unroll
    for (int j = 0; j < 4; j++) {
      float v = acc[i][j];
      if (mat <= 1) v = (v > 0.f) ? v + 1.f : expf(v);   // phi = elu + 1
      else if (mat == 3) v += bs[col + j];
      vals[j] = v;
    }
    float4 o = make_float4(vals[0], vals[1], vals[2], vals[3]);
    *(float4*)&Ob[row * DD + col] = o;
  }
}

// ---------------- 3. per-chunk sums: chunkS[b,c] = K_c^T V_c, chunkz[b,c] = sum K_c ----------------
__global__ __launch_bounds__(256) void chunksum_kernel(
    const float* __restrict__ Kb, const float* __restrict__ Vb,
    float* __restrict__ chunkS, float* __restrict__ chunkz)
{
  int c = blockIdx.x, b = blockIdx.y, tid = threadIdx.x;
  __shared__ float Ks[CLEN][DD];
  const float* Kc = Kb + (b * TT + c * CLEN) * DD;
  const float* Vc = Vb + (b * TT + c * CLEN) * DD;
  for (int u = 0; u < 8; u++) {
    int idx = u * 256 + tid;
    int t = idx >> 5, c4 = (idx & 31) * 4;
    *(float4*)&Ks[t][c4] = *(const float4*)&Kc[t * DD + c4];
  }
  __syncthreads();
  int ti = tid >> 4, tj = tid & 15;
  int i0 = ti * 8, j0 = tj * 8;
  float acc[8][8] = {};
  for (int t = 0; t < CLEN; t++) {
    float kv[8], vv[8];
    *(float4*)&kv[0] = *(const float4*)&Ks[t][i0];
    *(float4*)&kv[4] = *(const float4*)&Ks[t][i0 + 4];
    *(float4*)&vv[0] = *(const float4*)&Vc[t * DD + j0];
    *(float4*)&vv[4] = *(const float4*)&Vc[t * DD + j0 + 4];
#pragma unroll
    for (int i = 0; i < 8; i++)
#pragma unroll
      for (int j = 0; j < 8; j++) acc[i][j] += kv[i] * vv[j];
  }
  float* oS = chunkS + (b * NCH + c) * DD * DD;
#pragma unroll
  for (int i = 0; i < 8; i++) {
    *(float4*)&oS[(i0 + i) * DD + j0]     = *(float4*)&acc[i][0];
    *(float4*)&oS[(i0 + i) * DD + j0 + 4] = *(float4*)&acc[i][4];
  }
  if (tid < DD) {
    float z = 0.f;
    for (int t = 0; t < CLEN; t++) z += Ks[t][tid];
    chunkz[(b * NCH + c) * DD + tid] = z;
  }
}

// ---------------- 4. exclusive scans over chunks (S0/Z0 folded in; exact since S0=Z0=0
//                  and |cumsum| << 1e20 makes clip placement inert) ----------------
__global__ __launch_bounds__(256) void scan_s_kernel(
    const float* __restrict__ chunkS, const float* __restrict__ S0,
    float* __restrict__ prefS)
{
  int b = blockIdx.y;
  int idx = blockIdx.x * 256 + threadIdx.x;   // 0..16383
  float s0v = S0[b * DD * DD + idx];
  float acc = 0.f;
  for (int c = 0; c < NCH; c++) {
    prefS[(b * NCH + c) * DD * DD + idx] = acc + s0v;
    acc += chunkS[(b * NCH + c) * DD * DD + idx];
  }
}

__global__ __launch_bounds__(128) void scan_z_kernel(
    const float* __restrict__ chunkz, const float* __restrict__ Z0,
    float* __restrict__ prefz)
{
  int b = blockIdx.x, i = threadIdx.x;
  float z0v = Z0[b * DD + i];
  float acc = 0.f;
  for (int c = 0; c < NCH; c++) {
    prefz[(b * NCH + c) * DD + i] = acc + z0v;
    acc += chunkz[(b * NCH + c) * DD + i];
  }
}

// ---------------- 5. the hot kernel: stream S out (256 MiB). block = (jt, c, b),
//                  per-thread 4x(float4) running state, float4 stores ----------------
__global__ __launch_bounds__(256) void s_write_kernel(
    const float* __restrict__ Kb, const float* __restrict__ Vb,
    const float* __restrict__ prefS, float* __restrict__ Sout)
{
  int jt = blockIdx.x, c = blockIdx.y, b = blockIdx.z;
  __shared__ float Ks[CLEN][DD];
  __shared__ float Vs[CLEN][32];
  int tid = threadIdx.x;
  const float* Kc = Kb + (b * TT + c * CLEN) * DD;
  const float* Vc = Vb + (b * TT + c * CLEN) * DD + jt * 32;
  for (int u = 0; u < 8; u++) {
    int idx = u * 256 + tid;
    int t = idx >> 5, c4 = (idx & 31) * 4;
    *(float4*)&Ks[t][c4] = *(const float4*)&Kc[t * DD + c4];
  }
  for (int u = 0; u < 2; u++) {
    int idx = u * 256 + tid;
    int t = idx >> 3, c4 = (idx & 7) * 4;
    *(float4*)&Vs[t][c4] = *(const float4*)&Vc[t * DD + c4];
  }
  __syncthreads();
  int jq = tid & 7, irow = tid >> 3;
  int j = jt * 32 + jq * 4;
  float4 pref[4], acc[4];
#pragma unroll
  for (int p = 0; p < 4; p++) {
    int i = irow + 32 * p;
    pref[p] = *(const float4*)&prefS[(b * NCH + c) * DD * DD + i * DD + j];
    acc[p] = make_float4(0.f, 0.f, 0.f, 0.f);
  }
  float* So = Sout + (size_t)(b * TT + c * CLEN) * (DD * DD);
  for (int t = 0; t < CLEN; t++) {
    float4 v4 = *(const float4*)&Vs[t][jq * 4];
#pragma unroll
    for (int p = 0; p < 4; p++) {
      int i = irow + 32 * p;
      float kk = Ks[t][i];
      acc[p].x += kk * v4.x; acc[p].y += kk * v4.y;
      acc[p].z += kk * v4.z; acc[p].w += kk * v4.w;
      float4 o;
      o.x = fminf(fmaxf(pref[p].x + acc[p].x, -CLAMPV), CLAMPV);
      o.y = fminf(fmaxf(pref[p].y + acc[p].y, -CLAMPV), CLAMPV);
      o.z = fminf(fmaxf(pref[p].z + acc[p].z, -CLAMPV), CLAMPV);
      o.w = fminf(fmaxf(pref[p].w + acc[p].w, -CLAMPV), CLAMPV);
      *(float4*)&So[(size_t)t * (DD * DD) + i * DD + j] = o;
    }
  }
}

// ---------------- 6a. masked scores = tril(Q_c K_c^T) -> ws; Z output ----------------
__global__ __launch_bounds__(256) void attn_a_kernel(
    const float* __restrict__ Kb, const float* __restrict__ Qb,
    const float* __restrict__ prefz, float* __restrict__ scores,
    float* __restrict__ Zout)
{
  int c = blockIdx.x, b = blockIdx.y, tid = threadIdx.x;
  __shared__ float KsT[DD][CLEN + 1];   // [k][tau]
  __shared__ float sc[CLEN][65];
  __shared__ float zeff[DD];
  const float* Kc = Kb + (b * TT + c * CLEN) * DD;
  const float* Qc = Qb + (b * TT + c * CLEN) * DD;
  for (int u = 0; u < 8; u++) {
    int idx = u * 256 + tid;
    int t = idx >> 5, c4 = (idx & 31) * 4;
    float4 v = *(const float4*)&Kc[t * DD + c4];
    KsT[c4 + 0][t] = v.x; KsT[c4 + 1][t] = v.y;
    KsT[c4 + 2][t] = v.z; KsT[c4 + 3][t] = v.w;
  }
  if (tid < DD) zeff[tid] = prefz[(b * NCH + c) * DD + tid];
  __syncthreads();
  int tn = tid & 15, tm = tid >> 4;
  float s[4][4] = {};
  for (int k4 = 0; k4 < 32; k4++) {
    float qv[4][4];
#pragma unroll
    for (int i = 0; i < 4; i++)
      *(float4*)&qv[i][0] = *(const float4*)&Qc[(tm * 4 + i) * DD + k4 * 4];
#pragma unroll
    for (int kk = 0; kk < 4; kk++) {
      int k = k4 * 4 + kk;
      float kv[4];
#pragma unroll
      for (int j = 0; j < 4; j++) kv[j] = KsT[k][tn * 4 + j];
#pragma unroll
      for (int i = 0; i < 4; i++)
#pragma unroll
        for (int j = 0; j < 4; j++) s[i][j] += qv[i][kk] * kv[j];
    }
  }
#pragma unroll
  for (int i = 0; i < 4; i++)
#pragma unroll
    for (int j = 0; j < 4; j++) {
      int t = tm * 4 + i, tau = tn * 4 + j;
      sc[t][tau] = (tau <= t) ? s[i][j] : 0.f;
    }
  __syncthreads();
  float* scg = scores + (b * NCH + c) * (CLEN * CLEN);
  for (int u = 0; u < 16; u++) {            // FIX: 4096 elements, not 1024
    int idx = u * 256 + tid;
    scg[idx] = sc[idx >> 6][idx & 63];
  }
  if (tid < DD) {
    int i = tid;
    float a = zeff[i];
    for (int t = 0; t < CLEN; t++) {
      a += KsT[i][t];
      Zout[(size_t)(b * TT + c * CLEN + t) * DD + i] = fminf(fmaxf(a, -CLAMPV), CLAMPV);
    }
  }
}

// ---------------- 6b. num = sc@V + Q@(prefS incl S0); den; out_attn = num/den ----------------
__global__ __launch_bounds__(256) void attn_b_kernel(
    const float* __restrict__ Qb, const float* __restrict__ Vb,
    const float* __restrict__ prefS, const float* __restrict__ prefz,
    const float* __restrict__ scores, float* __restrict__ attn_o)
{
  int c = blockIdx.x, b = blockIdx.y, tid = threadIdx.x;
  __shared__ float Qs[CLEN][129];
  __shared__ float sc[CLEN][65];
  __shared__ float zeff[DD];
  __shared__ float den[CLEN];
  const float* Qc = Qb + (b * TT + c * CLEN) * DD;
  const float* Vc = Vb + (b * TT + c * CLEN) * DD;
  for (int u = 0; u < 8; u++) {
    int idx = u * 256 + tid;
    int t = idx >> 5, c4 = (idx & 31) * 4;
    float4 v = *(const float4*)&Qc[t * DD + c4];
    Qs[t][c4 + 0] = v.x; Qs[t][c4 + 1] = v.y;
    Qs[t][c4 + 2] = v.z; Qs[t][c4 + 3] = v.w;
  }
  const float* scg = scores + (b * NCH + c) * CLEN * CLEN;
  for (int u = 0; u < 16; u++) {            // FIX: 4096 elements, not 1024
    int idx = u * 256 + tid;
    sc[idx >> 6][idx & 63] = scg[idx];
  }
  if (tid < DD) zeff[tid] = prefz[(b * NCH + c) * DD + tid];
  __syncthreads();
  if (tid < CLEN) {
    int t = tid;
    float d = 0.f;
    for (int tau = 0; tau < CLEN; tau++) d += sc[t][tau];
    float dz = 0.f;
    for (int k = 0; k < DD; k++) dz += Qs[t][k] * zeff[k];
    den[t] = d + dz + 1e-5f;
  }
  __syncthreads();
  int tl = tid & 31, tt = tid >> 5;
  int l0 = tl * 4, t0 = tt * 8;
  float num[8][4] = {};
  for (int tau = 0; tau < CLEN; tau++) {
    float4 v4 = *(const float4*)&Vc[tau * DD + l0];
    float ss[8];
#pragma unroll
    for (int ii = 0; ii < 8; ii++) ss[ii] = sc[t0 + ii][tau];
#pragma unroll
    for (int ii = 0; ii < 8; ii++) {
      num[ii][0] += ss[ii] * v4.x; num[ii][1] += ss[ii] * v4.y;
      num[ii][2] += ss[ii] * v4.z; num[ii][3] += ss[ii] * v4.w;
    }
  }
  const float* P = prefS + (b * NCH + c) * DD * DD;
  for (int i = 0; i < DD; i++) {
    float4 p4 = *(const float4*)&P[i * DD + l0];
    float qq[8];
#pragma unroll
    for (int ii = 0; ii < 8; ii++) qq[ii] = Qs[t0 + ii][i];
#pragma unroll
    for (int ii = 0; ii < 8; ii++) {
      num[ii][0] += qq[ii] * p4.x; num[ii][1] += qq[ii] * p4.y;
      num[ii][2] += qq[ii] * p4.z; num[ii][3] += qq[ii] * p4.w;
    }
  }
  float* og = attn_o + (size_t)(b * TT + c * CLEN) * DD;
#pragma unroll
  for (int ii = 0; ii < 8; ii++) {
    float dd = den[t0 + ii];
    float4 o = make_float4(num[ii][0] / dd, num[ii][1] / dd,
                           num[ii][2] / dd, num[ii][3] / dd);
    *(float4*)&og[(t0 + ii) * DD + l0] = o;
  }
}

// ---------------- 7. FFN + residual ----------------
__global__ __launch_bounds__(256) void ffn_kernel(
    const float* __restrict__ att, const float* __restrict__ res,
    const float* __restrict__ W1, const float* __restrict__ b1,
    const float* __restrict__ W2, const float* __restrict__ b2,
    float* __restrict__ outp)
{
  int rt = blockIdx.x, tid = threadIdx.x;
  __shared__ float As[32][129];
  __shared__ float H1[32][129];
  const float* ab = att + rt * 32 * DD;
  for (int u = 0; u < 4; u++) {
    int idx = u * 256 + tid;
    int r = idx >> 5, c4 = (idx & 31) * 4;
    float4 v = *(const float4*)&ab[r * DD + c4];
    As[r][c4 + 0] = v.x; As[r][c4 + 1] = v.y;
    As[r][c4 + 2] = v.z; As[r][c4 + 3] = v.w;
  }
  __syncthreads();
  int cn = tid & 31, rm = tid >> 5;
  int col = cn * 4, r0 = rm * 4;
  float acc[4][4] = {};
  for (int k = 0; k < DD; k++) {
    float4 w = *(const float4*)&W1[k * DD + col];
    float a[4];
#pragma unroll
    for (int i = 0; i < 4; i++) a[i] = As[r0 + i][k];
#pragma unroll
    for (int i = 0; i < 4; i++) {
      acc[i][0] += a[i] * w.x; acc[i][1] += a[i] * w.y;
      acc[i][2] += a[i] * w.z; acc[i][3] += a[i] * w.w;
    }
  }
  float4 bv = *(const float4*)&b1[col];
#pragma unroll
  for (int i = 0; i < 4; i++) {
    H1[r0 + i][col + 0] = fmaxf(acc[i][0] + bv.x, 0.f);
    H1[r0 + i][col + 1] = fmaxf(acc[i][1] + bv.y, 0.f);
    H1[r0 + i][col + 2] = fmaxf(acc[i][2] + bv.z, 0.f);
    H1[r0 + i][col + 3] = fmaxf(acc[i][3] + bv.w, 0.f);
  }
  __syncthreads();
  float acc2[4][4] = {};
  for (int k = 0; k < DD; k++) {
    float4 w = *(const float4*)&W2[k * DD + col];
    float a[4];
#pragma unroll
    for (int i = 0; i < 4; i++) a[i] = H1[r0 + i][k];
#pragma unroll
    for (int i = 0; i < 4; i++) {
      acc2[i][0] += a[i] * w.x; acc2[i][1] += a[i] * w.y;
      acc2[i][2] += a[i] * w.z; acc2[i][3] += a[i] * w.w;
    }
  }
  float4 b2v = *(const float4*)&b2[col];
#pragma unroll
  for (int i = 0; i < 4; i++) {
    int row = rt * 32 + r0 + i;
    float4 rv = *(const float4*)&res[row * DD + col];
    float4 o;
    o.x = fmaxf(acc2[i][0] + b2v.x, 0.f) + rv.x;
    o.y = fmaxf(acc2[i][1] + b2v.y, 0.f) + rv.y;
    o.z = fmaxf(acc2[i][2] + b2v.z, 0.f) + rv.z;
    o.w = fmaxf(acc2[i][3] + b2v.w, 0.f) + rv.w;
    *(float4*)&outp[row * DD + col] = o;
  }
}

extern "C" void kernel_launch(void* const* d_in, const int* in_sizes, int n_in,
                              void* d_out, int out_size, void* d_ws, size_t ws_size,
                              hipStream_t stream)
{
  const float* x     = (const float*)d_in[0];
  const float* S0    = (const float*)d_in[1];
  const float* Z0    = (const float*)d_in[2];
  const float* gamma = (const float*)d_in[3];
  const float* beta  = (const float*)d_in[4];
  const float* Wk    = (const float*)d_in[5];
  const float* Wq    = (const float*)d_in[6];
  const float* Wv    = (const float*)d_in[7];
  const float* W1    = (const float*)d_in[8];
  const float* b1    = (const float*)d_in[9];
  const float* W2    = (const float*)d_in[10];
  const float* b2    = (const float*)d_in[11];
  const float* Ws    = (const float*)d_in[12];
  const float* bs    = (const float*)d_in[13];

  float* out_main = (float*)d_out;                       // [B,T,D]
  float* Sout = out_main + NROW * DD;                    // [B,T,D*D]
  float* Zout = Sout + (size_t)NROW * DD * DD;           // [B,T,D]

  // workspace layout (floats), total ~24.2 MB
  float* ws_f   = (float*)d_ws;
  float* xn     = ws_f;                  // 1048576
  float* Kb     = xn + 1048576;          // 524288
  float* Qb     = Kb + 524288;           // 524288
  float* Vb     = Qb + 524288;           // 524288
  float* Rb     = Vb + 524288;           // 524288  (xn@Ws + bs)
  float* chunkS = Rb + 524288;           // 1048576
  float* prefS  = chunkS + 1048576;      // 1048576 (exclusive prefix + S0)
  float* chunkz = prefS + 1048576;       // 8192
  float* prefz  = chunkz + 8192;         // 8192    (exclusive prefix + Z0)
  float* scb    = prefz + 8192;          // 262144  (masked scores)
  float* attn_o = scb + 262144;          // 524288

  ln_kernel<<<NROW, 256, 0, stream>>>(x, gamma, beta, xn);
  gemm_qkvs<<<dim3(8, 64), 256, 0, stream>>>(xn, Wk, Wq, Wv, Ws, bs, Kb, Qb, Vb, Rb);
  chunksum_kernel<<<dim3(NCH, BB), 256, 0, stream>>>(Kb, Vb, chunkS, chunkz);
  scan_s_kernel<<<dim3(64, BB), 256, 0, stream>>>(chunkS, S0, prefS);
  scan_z_kernel<<<BB, 128, 0, stream>>>(chunkz, Z0, prefz);
  s_write_kernel<<<dim3(4, NCH, BB), 256, 0, stream>>>(Kb, Vb, prefS, Sout);
  attn_a_kernel<<<dim3(NCH, BB), 256, 0, stream>>>(Kb, Qb, prefz, scb, Zout);
  attn_b_kernel<<<dim3(NCH, BB), 256, 0, stream>>>(Qb, Vb, prefS, prefz, scb, attn_o);
  ffn_kernel<<<NROW / 32, 256, 0, stream>>>(attn_o, Rb, W1, b1, W2, b2, out_main);
}

// Round 3
// 417.585 us; speedup vs baseline: 1.0342x; 1.0342x over previous
//
#include <hip/hip_runtime.h>

// LinearAttentionBlock: B=8 T=512 FIN=256 D=128
// out   [B,T,D]    @ d_out + 0
// S_out [B,T,D*D]  @ d_out + 524288      (256 MiB -> HBM-write bound floor ~45us @5.9TB/s)
// Z     [B,T,D]    @ d_out + 524288 + 67108864

constexpr int BB = 8, TT = 512, FIN_ = 256, DD = 128;
constexpr int NROW = BB * TT;       // 4096
constexpr int CLEN = 64, NCH = 8;   // chunk length, chunks per batch (T = CLEN*NCH)
constexpr float CLAMPV = 1e20f;

// ---------------- 1. LayerNorm: one wave per row, shuffle reduction, no barriers ----------------
__global__ __launch_bounds__(256) void ln_kernel(
    const float* __restrict__ x, const float* __restrict__ gamma,
    const float* __restrict__ beta, float* __restrict__ xn)
{
  int tid = threadIdx.x;
  int row = blockIdx.x * 4 + (tid >> 6);
  int lane = tid & 63;
  float4 v = *(const float4*)&x[row * FIN_ + lane * 4];
  float sum = v.x + v.y + v.z + v.w;
  float sq  = v.x * v.x + v.y * v.y + v.z * v.z + v.w * v.w;
#pragma unroll
  for (int off = 1; off < 64; off <<= 1) {
    sum += __shfl_xor(sum, off);
    sq  += __shfl_xor(sq, off);
  }
  float mu  = sum * (1.0f / FIN_);
  float var = sq * (1.0f / FIN_) - mu * mu;
  float rs  = rsqrtf(var + 1e-5f);
  float4 g = *(const float4*)&gamma[lane * 4];
  float4 b = *(const float4*)&beta[lane * 4];
  float4 o;
  o.x = (v.x - mu) * rs * g.x + b.x;
  o.y = (v.y - mu) * rs * g.y + b.y;
  o.z = (v.z - mu) * rs * g.z + b.z;
  o.w = (v.w - mu) * rs * g.w + b.w;
  *(float4*)&xn[row * FIN_ + lane * 4] = o;
}

// ---------------- 2. xn @ {Wk,Wq,Wv,Ws} fused GEMM, 64x64 tiles, 4x4 micro ----------------
__global__ __launch_bounds__(256) void gemm_qkvs(
    const float* __restrict__ xn,
    const float* __restrict__ Wk, const float* __restrict__ Wq,
    const float* __restrict__ Wv, const float* __restrict__ Ws,
    const float* __restrict__ bs,
    float* __restrict__ Kb, float* __restrict__ Qb,
    float* __restrict__ Vb, float* __restrict__ Rb)
{
  int ct = blockIdx.x, rt = blockIdx.y;
  int mat = ct >> 1, cb = (ct & 1) * 64;
  const float* W = (mat == 0) ? Wk : (mat == 1) ? Wq : (mat == 2) ? Wv : Ws;
  float* Ob      = (mat == 0) ? Kb : (mat == 1) ? Qb : (mat == 2) ? Vb : Rb;
  __shared__ float As[16][64];   // [k][m]
  __shared__ float Bs[16][64];   // [k][n]
  int tid = threadIdx.x;
  int tn = tid & 15, tm = tid >> 4;
  int lm = tid >> 2, lq = tid & 3;
  int lk = tid >> 4, ln4 = (tid & 15) * 4;
  float acc[4][4] = {};
  for (int k0 = 0; k0 < FIN_; k0 += 16) {
    float4 av = *(const float4*)&xn[(rt * 64 + lm) * FIN_ + k0 + lq * 4];
    As[lq * 4 + 0][lm] = av.x;
    As[lq * 4 + 1][lm] = av.y;
    As[lq * 4 + 2][lm] = av.z;
    As[lq * 4 + 3][lm] = av.w;
    *(float4*)&Bs[lk][ln4] = *(const float4*)&W[(k0 + lk) * DD + cb + ln4];
    __syncthreads();
#pragma unroll
    for (int k = 0; k < 16; k++) {
      float4 a = *(const float4*)&As[k][tm * 4];
      float4 b = *(const float4*)&Bs[k][tn * 4];
      float ar[4] = {a.x, a.y, a.z, a.w};
      float br[4] = {b.x, b.y, b.z, b.w};
#pragma unroll
      for (int i = 0; i < 4; i++)
#pragma unroll
        for (int j = 0; j < 4; j++) acc[i][j] += ar[i] * br[j];
    }
    __syncthreads();
  }
#pragma unroll
  for (int i = 0; i < 4; i++) {
    int row = rt * 64 + tm * 4 + i;
    int col = cb + tn * 4;
    float vals[4];
#pragma unroll
    for (int j = 0; j < 4; j++) {
      float v = acc[i][j];
      if (mat <= 1) v = (v > 0.f) ? v + 1.f : expf(v);   // phi = elu + 1
      else if (mat == 3) v += bs[col + j];
      vals[j] = v;
    }
    float4 o = make_float4(vals[0], vals[1], vals[2], vals[3]);
    *(float4*)&Ob[row * DD + col] = o;
  }
}

// ---------------- 3. per-chunk sums, split over j: grid (4 jt, NCH, BB) = 256 blocks ----------------
__global__ __launch_bounds__(256) void chunksum_kernel(
    const float* __restrict__ Kb, const float* __restrict__ Vb,
    float* __restrict__ chunkS, float* __restrict__ chunkz)
{
  int jt = blockIdx.x, c = blockIdx.y, b = blockIdx.z, tid = threadIdx.x;
  __shared__ float Ks[CLEN][DD];    // 32 KB
  __shared__ float Vs[CLEN][32];    // 8 KB
  const float* Kc = Kb + (b * TT + c * CLEN) * DD;
  const float* Vc = Vb + (b * TT + c * CLEN) * DD + jt * 32;
  for (int u = 0; u < 8; u++) {
    int idx = u * 256 + tid;
    int t = idx >> 5, c4 = (idx & 31) * 4;
    *(float4*)&Ks[t][c4] = *(const float4*)&Kc[t * DD + c4];
  }
  for (int u = 0; u < 2; u++) {
    int idx = u * 256 + tid;
    int t = idx >> 3, c4 = (idx & 7) * 4;
    *(float4*)&Vs[t][c4] = *(const float4*)&Vc[t * DD + c4];
  }
  __syncthreads();
  int ti = tid >> 3, tj = tid & 7;     // i0 = ti*4 (0..124), local j = tj*4
  int i0 = ti * 4, jl = tj * 4;
  float acc[4][4] = {};
  for (int t = 0; t < CLEN; t++) {
    float4 kv = *(const float4*)&Ks[t][i0];
    float4 vv = *(const float4*)&Vs[t][jl];
    float kr[4] = {kv.x, kv.y, kv.z, kv.w};
    float vr[4] = {vv.x, vv.y, vv.z, vv.w};
#pragma unroll
    for (int i = 0; i < 4; i++)
#pragma unroll
      for (int j = 0; j < 4; j++) acc[i][j] += kr[i] * vr[j];
  }
  float* oS = chunkS + (b * NCH + c) * DD * DD + jt * 32;
#pragma unroll
  for (int i = 0; i < 4; i++)
    *(float4*)&oS[(i0 + i) * DD + jl] = *(float4*)&acc[i][0];
  if (jt == 0 && tid < DD) {
    float z = 0.f;
    for (int t = 0; t < CLEN; t++) z += Ks[t][tid];
    chunkz[(b * NCH + c) * DD + tid] = z;
  }
}

// ---------------- 4. exclusive scans over chunks (S0/Z0 folded in) ----------------
__global__ __launch_bounds__(256) void scan_s_kernel(
    const float* __restrict__ chunkS, const float* __restrict__ S0,
    float* __restrict__ prefS)
{
  int b = blockIdx.y;
  int idx = blockIdx.x * 256 + threadIdx.x;   // 0..16383
  float s0v = S0[b * DD * DD + idx];
  float acc = 0.f;
  for (int c = 0; c < NCH; c++) {
    prefS[(b * NCH + c) * DD * DD + idx] = acc + s0v;
    acc += chunkS[(b * NCH + c) * DD * DD + idx];
  }
}

__global__ __launch_bounds__(128) void scan_z_kernel(
    const float* __restrict__ chunkz, const float* __restrict__ Z0,
    float* __restrict__ prefz)
{
  int b = blockIdx.x, i = threadIdx.x;
  float z0v = Z0[b * DD + i];
  float acc = 0.f;
  for (int c = 0; c < NCH; c++) {
    prefz[(b * NCH + c) * DD + i] = acc + z0v;
    acc += chunkz[(b * NCH + c) * DD + i];
  }
}

// ---------------- 5. S streaming, v2: grid (16 it, NCH, BB) = 1024 blocks, 4/CU ----------------
// block owns state rows i0..i0+7, all 128 cols. Wave stores 2x512B contiguous rows per t.
__global__ __launch_bounds__(256) void s_write_kernel(
    const float* __restrict__ Kb, const float* __restrict__ Vb,
    const float* __restrict__ prefS, float* __restrict__ Sout)
{
  int it = blockIdx.x, c = blockIdx.y, b = blockIdx.z;
  int i0 = it * 8;
  __shared__ float Vs[CLEN][DD];    // 32 KB
  __shared__ float Ksm[CLEN][8];    // 2 KB
  int tid = threadIdx.x;
  const float* Kc = Kb + (b * TT + c * CLEN) * DD;
  const float* Vc = Vb + (b * TT + c * CLEN) * DD;
  for (int u = 0; u < 8; u++) {
    int idx = u * 256 + tid;
    int t = idx >> 5, c4 = (idx & 31) * 4;
    *(float4*)&Vs[t][c4] = *(const float4*)&Vc[t * DD + c4];
  }
  for (int u = 0; u < 2; u++) {
    int idx = u * 256 + tid;
    int t = idx >> 3, r = idx & 7;
    Ksm[t][r] = Kc[t * DD + i0 + r];
  }
  __syncthreads();
  int irow = tid >> 5, jq = tid & 31;
  int j = jq * 4;
  float4 pref = *(const float4*)&prefS[(b * NCH + c) * DD * DD + (i0 + irow) * DD + j];
  float4 acc = make_float4(0.f, 0.f, 0.f, 0.f);
  float* So = Sout + (size_t)(b * TT + c * CLEN) * (DD * DD) + (i0 + irow) * DD + j;
  for (int t = 0; t < CLEN; t++) {
    float4 v4 = *(const float4*)&Vs[t][j];
    float kk = Ksm[t][irow];
    acc.x += kk * v4.x; acc.y += kk * v4.y;
    acc.z += kk * v4.z; acc.w += kk * v4.w;
    float4 o;
    o.x = fminf(fmaxf(pref.x + acc.x, -CLAMPV), CLAMPV);
    o.y = fminf(fmaxf(pref.y + acc.y, -CLAMPV), CLAMPV);
    o.z = fminf(fmaxf(pref.z + acc.z, -CLAMPV), CLAMPV);
    o.w = fminf(fmaxf(pref.w + acc.w, -CLAMPV), CLAMPV);
    *(float4*)&So[(size_t)t * (DD * DD)] = o;
  }
}

// ---------------- 6. fused attention: scores in LDS, Z, num/den, out ----------------
__global__ __launch_bounds__(256) void attn_kernel(
    const float* __restrict__ Kb, const float* __restrict__ Qb,
    const float* __restrict__ Vb, const float* __restrict__ prefS,
    const float* __restrict__ prefz,
    float* __restrict__ Zout, float* __restrict__ attn_o)
{
  int c = blockIdx.x, b = blockIdx.y, tid = threadIdx.x;
  __shared__ float KsT[DD][CLEN + 1];   // [k][tau]  33 KB
  __shared__ float Qs[CLEN][DD + 1];    // [t][k]    33 KB
  __shared__ float sc[CLEN][65];        //           16.6 KB
  __shared__ float zeff[DD];
  __shared__ float den[CLEN];
  const float* Kc = Kb + (b * TT + c * CLEN) * DD;
  const float* Qc = Qb + (b * TT + c * CLEN) * DD;
  const float* Vc = Vb + (b * TT + c * CLEN) * DD;
  for (int u = 0; u < 8; u++) {
    int idx = u * 256 + tid;
    int t = idx >> 5, c4 = (idx & 31) * 4;
    float4 v = *(const float4*)&Kc[t * DD + c4];
    KsT[c4 + 0][t] = v.x; KsT[c4 + 1][t] = v.y;
    KsT[c4 + 2][t] = v.z; KsT[c4 + 3][t] = v.w;
    float4 q = *(const float4*)&Qc[t * DD + c4];
    Qs[t][c4 + 0] = q.x; Qs[t][c4 + 1] = q.y;
    Qs[t][c4 + 2] = q.z; Qs[t][c4 + 3] = q.w;
  }
  if (tid < DD) zeff[tid] = prefz[(b * NCH + c) * DD + tid];
  __syncthreads();
  // scores: tril(Q K^T)
  {
    int tn = tid & 15, tm = tid >> 4;
    float s[4][4] = {};
    for (int k4 = 0; k4 < 32; k4++) {
      float qv[4][4];
#pragma unroll
      for (int i = 0; i < 4; i++)
        *(float4*)&qv[i][0] = *(const float4*)&Qc[(tm * 4 + i) * DD + k4 * 4];
#pragma unroll
      for (int kk = 0; kk < 4; kk++) {
        int k = k4 * 4 + kk;
        float kv[4];
#pragma unroll
        for (int j = 0; j < 4; j++) kv[j] = KsT[k][tn * 4 + j];
#pragma unroll
        for (int i = 0; i < 4; i++)
#pragma unroll
          for (int j = 0; j < 4; j++) s[i][j] += qv[i][kk] * kv[j];
      }
    }
#pragma unroll
    for (int i = 0; i < 4; i++)
#pragma unroll
      for (int j = 0; j < 4; j++) {
        int t = tm * 4 + i, tau = tn * 4 + j;
        sc[t][tau] = (tau <= t) ? s[i][j] : 0.f;
      }
  }
  // Z output (independent of sc)
  if (tid < DD) {
    int i = tid;
    float a = zeff[i];
    for (int t = 0; t < CLEN; t++) {
      a += KsT[i][t];
      Zout[(size_t)(b * TT + c * CLEN + t) * DD + i] = fminf(fmaxf(a, -CLAMPV), CLAMPV);
    }
  }
  __syncthreads();
  if (tid < CLEN) {
    int t = tid;
    float d = 0.f;
    for (int tau = 0; tau < CLEN; tau++) d += sc[t][tau];
    float dz = 0.f;
    for (int k = 0; k < DD; k++) dz += Qs[t][k] * zeff[k];
    den[t] = d + dz + 1e-5f;
  }
  __syncthreads();
  int tl = tid & 31, tt = tid >> 5;
  int l0 = tl * 4, t0 = tt * 8;
  float num[8][4] = {};
  for (int tau = 0; tau < CLEN; tau++) {
    float4 v4 = *(const float4*)&Vc[tau * DD + l0];
    float ss[8];
#pragma unroll
    for (int ii = 0; ii < 8; ii++) ss[ii] = sc[t0 + ii][tau];
#pragma unroll
    for (int ii = 0; ii < 8; ii++) {
      num[ii][0] += ss[ii] * v4.x; num[ii][1] += ss[ii] * v4.y;
      num[ii][2] += ss[ii] * v4.z; num[ii][3] += ss[ii] * v4.w;
    }
  }
  const float* P = prefS + (b * NCH + c) * DD * DD;
  for (int i = 0; i < DD; i++) {
    float4 p4 = *(const float4*)&P[i * DD + l0];
    float qq[8];
#pragma unroll
    for (int ii = 0; ii < 8; ii++) qq[ii] = Qs[t0 + ii][i];
#pragma unroll
    for (int ii = 0; ii < 8; ii++) {
      num[ii][0] += qq[ii] * p4.x; num[ii][1] += qq[ii] * p4.y;
      num[ii][2] += qq[ii] * p4.z; num[ii][3] += qq[ii] * p4.w;
    }
  }
  float* og = attn_o + (size_t)(b * TT + c * CLEN) * DD;
#pragma unroll
  for (int ii = 0; ii < 8; ii++) {
    float dd = den[t0 + ii];
    float4 o = make_float4(num[ii][0] / dd, num[ii][1] / dd,
                           num[ii][2] / dd, num[ii][3] / dd);
    *(float4*)&og[(t0 + ii) * DD + l0] = o;
  }
}

// ---------------- 7. FFN + residual ----------------
__global__ __launch_bounds__(256) void ffn_kernel(
    const float* __restrict__ att, const float* __restrict__ res,
    const float* __restrict__ W1, const float* __restrict__ b1,
    const float* __restrict__ W2, const float* __restrict__ b2,
    float* __restrict__ outp)
{
  int rt = blockIdx.x, tid = threadIdx.x;
  __shared__ float As[32][129];
  __shared__ float H1[32][129];
  const float* ab = att + rt * 32 * DD;
  for (int u = 0; u < 4; u++) {
    int idx = u * 256 + tid;
    int r = idx >> 5, c4 = (idx & 31) * 4;
    float4 v = *(const float4*)&ab[r * DD + c4];
    As[r][c4 + 0] = v.x; As[r][c4 + 1] = v.y;
    As[r][c4 + 2] = v.z; As[r][c4 + 3] = v.w;
  }
  __syncthreads();
  int cn = tid & 31, rm = tid >> 5;
  int col = cn * 4, r0 = rm * 4;
  float acc[4][4] = {};
  for (int k = 0; k < DD; k++) {
    float4 w = *(const float4*)&W1[k * DD + col];
    float a[4];
#pragma unroll
    for (int i = 0; i < 4; i++) a[i] = As[r0 + i][k];
#pragma unroll
    for (int i = 0; i < 4; i++) {
      acc[i][0] += a[i] * w.x; acc[i][1] += a[i] * w.y;
      acc[i][2] += a[i] * w.z; acc[i][3] += a[i] * w.w;
    }
  }
  float4 bv = *(const float4*)&b1[col];
#pragma unroll
  for (int i = 0; i < 4; i++) {
    H1[r0 + i][col + 0] = fmaxf(acc[i][0] + bv.x, 0.f);
    H1[r0 + i][col + 1] = fmaxf(acc[i][1] + bv.y, 0.f);
    H1[r0 + i][col + 2] = fmaxf(acc[i][2] + bv.z, 0.f);
    H1[r0 + i][col + 3] = fmaxf(acc[i][3] + bv.w, 0.f);
  }
  __syncthreads();
  float acc2[4][4] = {};
  for (int k = 0; k < DD; k++) {
    float4 w = *(const float4*)&W2[k * DD + col];
    float a[4];
#pragma unroll
    for (int i = 0; i < 4; i++) a[i] = H1[r0 + i][k];
#pragma unroll
    for (int i = 0; i < 4; i++) {
      acc2[i][0] += a[i] * w.x; acc2[i][1] += a[i] * w.y;
      acc2[i][2] += a[i] * w.z; acc2[i][3] += a[i] * w.w;
    }
  }
  float4 b2v = *(const float4*)&b2[col];
#pragma unroll
  for (int i = 0; i < 4; i++) {
    int row = rt * 32 + r0 + i;
    float4 rv = *(const float4*)&res[row * DD + col];
    float4 o;
    o.x = fmaxf(acc2[i][0] + b2v.x, 0.f) + rv.x;
    o.y = fmaxf(acc2[i][1] + b2v.y, 0.f) + rv.y;
    o.z = fmaxf(acc2[i][2] + b2v.z, 0.f) + rv.z;
    o.w = fmaxf(acc2[i][3] + b2v.w, 0.f) + rv.w;
    *(float4*)&outp[row * DD + col] = o;
  }
}

extern "C" void kernel_launch(void* const* d_in, const int* in_sizes, int n_in,
                              void* d_out, int out_size, void* d_ws, size_t ws_size,
                              hipStream_t stream)
{
  const float* x     = (const float*)d_in[0];
  const float* S0    = (const float*)d_in[1];
  const float* Z0    = (const float*)d_in[2];
  const float* gamma = (const float*)d_in[3];
  const float* beta  = (const float*)d_in[4];
  const float* Wk    = (const float*)d_in[5];
  const float* Wq    = (const float*)d_in[6];
  const float* Wv    = (const float*)d_in[7];
  const float* W1    = (const float*)d_in[8];
  const float* b1    = (const float*)d_in[9];
  const float* W2    = (const float*)d_in[10];
  const float* b2    = (const float*)d_in[11];
  const float* Ws    = (const float*)d_in[12];
  const float* bs    = (const float*)d_in[13];

  float* out_main = (float*)d_out;                       // [B,T,D]
  float* Sout = out_main + NROW * DD;                    // [B,T,D*D]
  float* Zout = Sout + (size_t)NROW * DD * DD;           // [B,T,D]

  float* ws_f   = (float*)d_ws;
  float* xn     = ws_f;                  // 1048576
  float* Kb     = xn + 1048576;          // 524288
  float* Qb     = Kb + 524288;           // 524288
  float* Vb     = Qb + 524288;           // 524288
  float* Rb     = Vb + 524288;           // 524288  (xn@Ws + bs)
  float* chunkS = Rb + 524288;           // 1048576
  float* prefS  = chunkS + 1048576;      // 1048576 (exclusive prefix + S0)
  float* chunkz = prefS + 1048576;       // 8192
  float* prefz  = chunkz + 8192;         // 8192    (exclusive prefix + Z0)
  float* attn_o = prefz + 8192;          // 524288

  ln_kernel<<<NROW / 4, 256, 0, stream>>>(x, gamma, beta, xn);
  gemm_qkvs<<<dim3(8, 64), 256, 0, stream>>>(xn, Wk, Wq, Wv, Ws, bs, Kb, Qb, Vb, Rb);
  chunksum_kernel<<<dim3(4, NCH, BB), 256, 0, stream>>>(Kb, Vb, chunkS, chunkz);
  scan_s_kernel<<<dim3(64, BB), 256, 0, stream>>>(chunkS, S0, prefS);
  scan_z_kernel<<<BB, 128, 0, stream>>>(chunkz, Z0, prefz);
  s_write_kernel<<<dim3(16, NCH, BB), 256, 0, stream>>>(Kb, Vb, prefS, Sout);
  attn_kernel<<<dim3(NCH, BB), 256, 0, stream>>>(Kb, Qb, Vb, prefS, prefz, Zout, attn_o);
  ffn_kernel<<<NROW / 32, 256, 0, stream>>>(attn_o, Rb, W1, b1, W2, b2, out_main);
}